// Round 12
// baseline (265.898 us; speedup 1.0000x reference)
//
#include <hip/hip_runtime.h>

#define D 128
#define KTOT 256
#define GM 128
#define LPAD 8
#define LSTR (KTOT + LPAD)   // 264

#define EB1   8192    // edges per pass-1 block
#define BKT_W 64      // nodes per coarse bucket
#define WIN   1024    // buckets per scatter window
#define EMAX  8192    // max edges per bucket handled in LDS (mean 1024)
#define HB1MAX 2048   // max coarse buckets (supports n_nodes <= 131072)

typedef __attribute__((ext_vector_type(8))) short bf16x8;
typedef __attribute__((ext_vector_type(4))) float f32x4;

__device__ __forceinline__ unsigned short f2b(float f) {
    unsigned int u = __float_as_uint(f);
    u += 0x7fffu + ((u >> 16) & 1u);   // RNE (inputs are finite)
    return (unsigned short)(u >> 16);
}
__device__ __forceinline__ float blo(unsigned int u) { return __uint_as_float(u << 16); }
__device__ __forceinline__ float bhi(unsigned int u) { return __uint_as_float(u & 0xffff0000u); }

// ---------------------------------------------------------------------------
// Fused pack + pass-1 count
// ---------------------------------------------------------------------------
__global__ __launch_bounds__(256) void pack_count_kernel(
    const void* __restrict__ ei, unsigned int* __restrict__ pk,
    unsigned short* __restrict__ bkt, int n_edges, int nb1,
    int* __restrict__ C)
{
    __shared__ int h[HB1MAX];
    for (int i = threadIdx.x; i < nb1; i += 256) h[i] = 0;

    const unsigned int* eiu = (const unsigned int*)ei;
    const int l = threadIdx.x & 63;
    unsigned int w0 = eiu[2 * l + 1];
    unsigned int w1 = eiu[2 * (l + 64) + 1];
    const int is64 = __all((w0 | w1) == 0u);
    __syncthreads();

    const int e0 = blockIdx.x * EB1;
    const int e1 = min(e0 + EB1, n_edges);
    for (int e = e0 + threadIdx.x; e < e1; e += 256) {
        int s, d;
        if (is64) {
            const long long* p = (const long long*)ei;
            s = (int)p[e]; d = (int)p[n_edges + e];
        } else {
            const int* p = (const int*)ei;
            s = p[e]; d = p[n_edges + e];
        }
        pk[e]  = ((unsigned int)s << 6) | (unsigned int)(d & (BKT_W - 1));
        int b = d >> 6;
        bkt[e] = (unsigned short)b;
        atomicAdd(&h[b], 1);
    }
    __syncthreads();
    int* out = C + (long long)blockIdx.x * nb1;
    for (int i = threadIdx.x; i < nb1; i += 256) out[i] = h[i];
}

// ---------------------------------------------------------------------------
// Flat exclusive scan of C in bucket-major order (block-local part)
// ---------------------------------------------------------------------------
__global__ __launch_bounds__(1024) void scanA_kernel(
    const int* __restrict__ C, int* __restrict__ Cs,
    int* __restrict__ blockSums, int L, int nb1, int nblk1)
{
    __shared__ int sm[1024];
    const int tid = threadIdx.x;
    const int i = blockIdx.x * 1024 + tid;
    int v = 0;
    if (i < L) {
        int b = i / nblk1, k = i - b * nblk1;
        v = C[(long long)k * nb1 + b];
    }
    int val = v;
    sm[tid] = val;
    __syncthreads();
    for (int off = 1; off < 1024; off <<= 1) {
        int t = (tid >= off) ? sm[tid - off] : 0;
        __syncthreads();
        val += t;
        sm[tid] = val;
        __syncthreads();
    }
    if (i < L) Cs[i] = val - v;
    if (tid == 1023) blockSums[blockIdx.x] = val;
}

// scan3: each block reduces blockSums[0..blockIdx) itself (nbL <= 1024)
__global__ __launch_bounds__(1024) void scan3_kernel(
    int* __restrict__ arr, const int* __restrict__ blockSums, int n)
{
    __shared__ int sm[1024];
    const int tid = threadIdx.x;
    sm[tid] = (tid < blockIdx.x) ? blockSums[tid] : 0;
    __syncthreads();
    #pragma unroll
    for (int off = 512; off > 0; off >>= 1) {
        if (tid < off) sm[tid] += sm[tid + off];
        __syncthreads();
    }
    const int i = blockIdx.x * 1024 + tid;
    if (i < n) arr[i] += sm[0];
}

// ---------------------------------------------------------------------------
// Pass-1 scatter, all windows in one dispatch (win = blockIdx / nblk1)
// ---------------------------------------------------------------------------
__global__ __launch_bounds__(256) void s1_scatter_kernel(
    const unsigned short* __restrict__ bkt, const unsigned int* __restrict__ pk,
    const int* __restrict__ Cs, unsigned int* __restrict__ sorted,
    int n_edges, int nb1, int nblk1)
{
    __shared__ int cur[WIN];
    const int win = blockIdx.x / nblk1;
    const int blk = blockIdx.x - win * nblk1;
    const int lo  = win * WIN;
    const int hi  = min(lo + WIN, nb1);
    for (int t = threadIdx.x; t < hi - lo; t += 256)
        cur[t] = Cs[(long long)(lo + t) * nblk1 + blk];
    __syncthreads();
    const int e0 = blk * EB1;
    const int e1 = min(e0 + EB1, n_edges);
    for (int e = e0 + threadIdx.x; e < e1; e += 256) {
        int b = bkt[e];
        if (b >= lo && b < hi) {
            int pos = atomicAdd(&cur[b - lo], 1);   // LDS atomic
            sorted[pos] = pk[e];
        }
    }
}

// ---------------------------------------------------------------------------
// Merged: blocks [0,nb1) per-bucket LDS counting sort (row_end + sorted in
// place); blocks [nb1,nb1+nbcvt) cvt x f32->bf16; last 256 blocks build Wt.
// ---------------------------------------------------------------------------
__global__ __launch_bounds__(256) void sort_prep_kernel(
    unsigned int* __restrict__ sorted, const int* __restrict__ Cs,
    int n_edges, int n_nodes, int nb1, int nblk1, int* __restrict__ row_end,
    const float* __restrict__ x, unsigned short* __restrict__ Xb,
    long long nelem, int nbcvt,
    const float* __restrict__ Wr1, const float* __restrict__ Wl1,
    unsigned short* __restrict__ Wt1,
    const float* __restrict__ Wr2, const float* __restrict__ Wl2,
    unsigned short* __restrict__ Wt2)
{
    __shared__ unsigned int lpk[EMAX];
    __shared__ int h64[BKT_W], excl[BKT_W + 1], cur[BKT_W];
    const int bid = blockIdx.x;
    const int t = threadIdx.x;

    if (bid < nb1) {
        const int b = bid;
        const int base = Cs[(long long)b * nblk1];
        const int nextb = (b + 1 < nb1) ? Cs[(long long)(b + 1) * nblk1] : n_edges;
        const int cnt = min(nextb - base, EMAX);

        if (t < BKT_W) h64[t] = 0;
        for (int i = t; i < cnt; i += 256) lpk[i] = sorted[base + i];
        __syncthreads();
        for (int i = t; i < cnt; i += 256) atomicAdd(&h64[lpk[i] & (BKT_W - 1)], 1);
        __syncthreads();
        if (t == 0) {
            int run = 0;
            #pragma unroll
            for (int i = 0; i < BKT_W; ++i) { excl[i] = run; run += h64[i]; }
            excl[BKT_W] = run;
        }
        __syncthreads();
        const int node0 = b * BKT_W;
        const int bins = min(BKT_W, n_nodes - node0);
        if (t < bins) row_end[node0 + t] = base + excl[t + 1];
        if (t < BKT_W) cur[t] = excl[t];
        __syncthreads();
        for (int i = t; i < cnt; i += 256) {
            unsigned int p = lpk[i];
            int pos = atomicAdd(&cur[p & (BKT_W - 1)], 1);   // LDS atomic
            sorted[base + pos] = p >> 6;                     // src
        }
    } else if (bid < nb1 + nbcvt) {
        const long long i = ((long long)(bid - nb1) * 256 + t) * 8;
        if (i >= nelem) return;
        float4 a = *(const float4*)(x + i);
        float4 c2 = *(const float4*)(x + i + 4);
        bf16x8 v;
        v[0] = (short)f2b(a.x);  v[1] = (short)f2b(a.y);
        v[2] = (short)f2b(a.z);  v[3] = (short)f2b(a.w);
        v[4] = (short)f2b(c2.x); v[5] = (short)f2b(c2.y);
        v[6] = (short)f2b(c2.z); v[7] = (short)f2b(c2.w);
        *(bf16x8*)(Xb + i) = v;
    } else {
        const int cb = bid - nb1 - nbcvt;         // 0..255
        const float* Wr = (cb < 128) ? Wr1 : Wr2;
        const float* Wl = (cb < 128) ? Wl1 : Wl2;
        unsigned short* Wt = (cb < 128) ? Wt1 : Wt2;
        const int c = cb & 127;
        const int k = t;
        float v = (k < 128) ? Wr[k * D + c] : Wl[(k - 128) * D + c];
        Wt[c * KTOT + k] = f2b(v);
    }
}

// ---------------------------------------------------------------------------
// FUSED layer: out = relu(X @ Wr + (sum_{src} X[src]) @ Wl + b) per 128-row
// tile. Phase 1: the 4 lanes sharing lr (q=0..3) gather-accumulate node
// w*16+lr's neighbor sum in registers, ALREADY in MFMA A-fragment layout
// (lane q holds cols t*32 + q*8 + j). Phase 2: f2b-pack -> MFMA (X from
// global own rows, AGG from registers, Wt from LDS). No intermediate buffer.
// ---------------------------------------------------------------------------
#define ACCQ(t, u) { agf[t][0] += blo(u.x); agf[t][1] += bhi(u.x); \
                     agf[t][2] += blo(u.y); agf[t][3] += bhi(u.y); \
                     agf[t][4] += blo(u.z); agf[t][5] += bhi(u.z); \
                     agf[t][6] += blo(u.w); agf[t][7] += bhi(u.w); }

template <int OUT_BF16>
__global__ __launch_bounds__(512, 4) void fused_layer_kernel(
    const unsigned short* __restrict__ Xop, const int* __restrict__ sorted_src,
    const int* __restrict__ row_end, const unsigned short* __restrict__ Wt,
    const float* __restrict__ bias, void* outp, int n)
{
    __shared__ short sW[D][LSTR];
    const int tid = threadIdx.x;
    const int r0 = blockIdx.x * GM;

    // stage Wt
    for (int i = 0; i < 8; ++i) {
        int idx = tid + i * 512;
        int r = idx >> 5, c8 = idx & 31;
        bf16x8 w = *(const bf16x8*)(Wt + r * KTOT + c8 * 8);
        *(bf16x8*)&sW[r][c8 * 8] = w;
    }

    const int w    = tid >> 6;
    const int lane = tid & 63;
    const int lr   = lane & 15;
    const int q8   = (lane >> 4) * 8;
    const int row  = r0 + w * 16 + lr;
    const bool rok = (row < n);

    // ---- phase 1: register gather-aggregate (frag layout) ----
    float agf[4][8];
    #pragma unroll
    for (int t = 0; t < 4; ++t)
        #pragma unroll
        for (int j = 0; j < 8; ++j) agf[t][j] = 0.f;

    int beg = 0, end = 0;
    if (rok) {
        beg = row ? row_end[row - 1] : 0;
        end = row_end[row];
    }
    int i = beg;
    for (; i + 1 < end; i += 2) {
        int s0 = sorted_src[i];
        int s1 = sorted_src[i + 1];
        const unsigned short* rb0 = Xop + (size_t)s0 * D + q8;
        const unsigned short* rb1 = Xop + (size_t)s1 * D + q8;
        uint4 u0 = *(const uint4*)(rb0);
        uint4 u1 = *(const uint4*)(rb0 + 32);
        uint4 u2 = *(const uint4*)(rb0 + 64);
        uint4 u3 = *(const uint4*)(rb0 + 96);
        uint4 v0 = *(const uint4*)(rb1);
        uint4 v1 = *(const uint4*)(rb1 + 32);
        uint4 v2 = *(const uint4*)(rb1 + 64);
        uint4 v3 = *(const uint4*)(rb1 + 96);
        ACCQ(0, u0); ACCQ(1, u1); ACCQ(2, u2); ACCQ(3, u3);
        ACCQ(0, v0); ACCQ(1, v1); ACCQ(2, v2); ACCQ(3, v3);
    }
    if (i < end) {
        int s0 = sorted_src[i];
        const unsigned short* rb0 = Xop + (size_t)s0 * D + q8;
        uint4 u0 = *(const uint4*)(rb0);
        uint4 u1 = *(const uint4*)(rb0 + 32);
        uint4 u2 = *(const uint4*)(rb0 + 64);
        uint4 u3 = *(const uint4*)(rb0 + 96);
        ACCQ(0, u0); ACCQ(1, u1); ACCQ(2, u2); ACCQ(3, u3);
    }

    // pack to bf16 A-fragments (same rounding as the old agg->bf16 store)
    bf16x8 afr[4];
    #pragma unroll
    for (int t = 0; t < 4; ++t) {
        #pragma unroll
        for (int j = 0; j < 8; ++j) afr[t][j] = (short)f2b(agf[t][j]);
    }

    __syncthreads();   // sW ready (also separates staging from MFMA reads)

    // ---- phase 2: MFMA ----
    f32x4 acc[8];
    #pragma unroll
    for (int ct = 0; ct < 8; ++ct) acc[ct] = (f32x4){0.f, 0.f, 0.f, 0.f};

    #pragma unroll
    for (int ks = 0; ks < 8; ++ks) {
        bf16x8 a;
        if (ks < 4) {
            a = (bf16x8){};
            if (rok)
                a = *(const bf16x8*)(Xop + (size_t)row * D + ks * 32 + q8);
        } else {
            a = afr[ks - 4];
        }
        #pragma unroll
        for (int ct = 0; ct < 8; ++ct) {
            bf16x8 bf = *(const bf16x8*)&sW[ct * 16 + lr][ks * 32 + q8];
            acc[ct] = __builtin_amdgcn_mfma_f32_16x16x32_bf16(a, bf, acc[ct], 0, 0, 0);
        }
    }

    // C/D: col = lane&15, row = (lane>>4)*4 + j
    const int rbase = r0 + w * 16 + (lane >> 4) * 4;
    #pragma unroll
    for (int ct = 0; ct < 8; ++ct) {
        const int col = ct * 16 + lr;
        const float bv = bias[col];
        #pragma unroll
        for (int j = 0; j < 4; ++j) {
            int orow = rbase + j;
            if (orow < n) {
                float val = fmaxf(acc[ct][j] + bv, 0.f);
                if (OUT_BF16) {
                    ((unsigned short*)outp)[(size_t)orow * D + col] = f2b(val);
                } else {
                    ((float*)outp)[(size_t)orow * D + col] = val;
                }
            }
        }
    }
}

static inline size_t align_up(size_t v, size_t a) { return (v + a - 1) & ~(a - 1); }

extern "C" void kernel_launch(void* const* d_in, const int* in_sizes, int n_in,
                              void* d_out, int out_size, void* d_ws, size_t ws_size,
                              hipStream_t stream) {
    const float* x   = (const float*)d_in[0];
    const void*  ei  = d_in[1];
    const float* Wr1 = (const float*)d_in[2];
    const float* Wl1 = (const float*)d_in[3];
    const float* b1  = (const float*)d_in[4];
    const float* Wr2 = (const float*)d_in[5];
    const float* Wl2 = (const float*)d_in[6];
    const float* b2  = (const float*)d_in[7];
    float* out = (float*)d_out;

    const int n_nodes = in_sizes[0] / D;
    const int n_edges = in_sizes[1] / 2;

    const int nb1   = (n_nodes + BKT_W - 1) / BKT_W;
    const int nblk1 = (n_edges + EB1 - 1) / EB1;
    const int L     = nb1 * nblk1;
    const int npass = (nb1 + WIN - 1) / WIN;
    const int nbL   = (L + 1023) / 1024;   // <= 1024 required by scan3

    // ws layout (~58 MB; proven available rounds 2-11)
    char* ws = (char*)d_ws;
    size_t off_rs   = 0;
    size_t off_bs   = align_up(off_rs + 4 * (size_t)(n_nodes + 1), 256);
    size_t off_ssrc = align_up(off_bs + 4 * 1024, 256);
    size_t off_wt1  = align_up(off_ssrc + 4 * (size_t)n_edges, 256);
    size_t off_wt2  = align_up(off_wt1 + 2 * (size_t)D * KTOT, 256);
    size_t off_xb   = align_up(off_wt2 + 2 * (size_t)D * KTOT, 256);
    size_t off_ab   = align_up(off_xb + 2 * (size_t)n_nodes * D, 256);

    int* row_end         = (int*)(ws + off_rs);
    int* blockSums       = (int*)(ws + off_bs);
    unsigned int* sorted = (unsigned int*)(ws + off_ssrc);
    unsigned short* Wt1  = (unsigned short*)(ws + off_wt1);
    unsigned short* Wt2  = (unsigned short*)(ws + off_wt2);
    unsigned short* Xb   = (unsigned short*)(ws + off_xb);
    unsigned short* Ab   = (unsigned short*)(ws + off_ab);
    // pk/bkt alias Xb (dead until sort_prep cvt); C/Cs alias Ab (dead after sort_prep)
    unsigned int*   pk  = (unsigned int*)(ws + off_xb);
    unsigned short* bkt = (unsigned short*)(pk + n_edges);
    int* C  = (int*)(ws + off_ab);
    int* Cs = C + L;

    const int gemm_blocks = (n_nodes + GM - 1) / GM;
    const long long nfeat = (long long)n_nodes * D;
    const int nbcvt = (int)((nfeat / 8 + 255) / 256);

    // ---- CSR build: two-level counting sort, zero global atomics ----
    pack_count_kernel<<<nblk1, 256, 0, stream>>>(ei, pk, bkt, n_edges, nb1, C);
    scanA_kernel<<<nbL, 1024, 0, stream>>>(C, Cs, blockSums, L, nb1, nblk1);
    scan3_kernel<<<nbL, 1024, 0, stream>>>(Cs, blockSums, L);
    s1_scatter_kernel<<<nblk1 * npass, 256, 0, stream>>>(
        bkt, pk, Cs, sorted, n_edges, nb1, nblk1);

    // ---- merged bucket-sort + prep (pk/bkt dead after scatter) ----
    sort_prep_kernel<<<nb1 + nbcvt + 256, 256, 0, stream>>>(
        sorted, Cs, n_edges, n_nodes, nb1, nblk1, row_end,
        x, Xb, nfeat, nbcvt, Wr1, Wl1, Wt1, Wr2, Wl2, Wt2);

    // ---- layer 1 fused (h bf16 -> Ab; Cs dead, safe to overwrite) ----
    fused_layer_kernel<1><<<gemm_blocks, 512, 0, stream>>>(
        Xb, (const int*)sorted, row_end, Wt1, b1, Ab, n_nodes);

    // ---- layer 2 fused (gather + X from Ab; f32 -> out) ----
    fused_layer_kernel<0><<<gemm_blocks, 512, 0, stream>>>(
        Ab, (const int*)sorted, row_end, Wt2, b2, out, n_nodes);
}

// Round 13
// 237.527 us; speedup vs baseline: 1.1194x; 1.1194x over previous
//
#include <hip/hip_runtime.h>

#define D 128
#define KTOT 256
#define GM 128
#define LPAD 8
#define LSTR (KTOT + LPAD)   // 264

#define EB1   8192    // edges per pass-1 block
#define BKT_W 64      // nodes per coarse bucket
#define WIN   1024    // buckets per scatter window
#define EMAX  8192    // max edges per bucket handled in LDS (mean 1024)
#define HB1MAX 2048   // max coarse buckets (supports n_nodes <= 131072)

typedef __attribute__((ext_vector_type(8))) short bf16x8;
typedef __attribute__((ext_vector_type(4))) float f32x4;

__device__ __forceinline__ unsigned short f2b(float f) {
    unsigned int u = __float_as_uint(f);
    u += 0x7fffu + ((u >> 16) & 1u);   // RNE (inputs are finite)
    return (unsigned short)(u >> 16);
}
__device__ __forceinline__ float blo(unsigned int u) { return __uint_as_float(u << 16); }
__device__ __forceinline__ float bhi(unsigned int u) { return __uint_as_float(u & 0xffff0000u); }

// ---------------------------------------------------------------------------
// Fused pack + pass-1 count
// ---------------------------------------------------------------------------
__global__ __launch_bounds__(256) void pack_count_kernel(
    const void* __restrict__ ei, unsigned int* __restrict__ pk,
    unsigned short* __restrict__ bkt, int n_edges, int nb1,
    int* __restrict__ C)
{
    __shared__ int h[HB1MAX];
    for (int i = threadIdx.x; i < nb1; i += 256) h[i] = 0;

    const unsigned int* eiu = (const unsigned int*)ei;
    const int l = threadIdx.x & 63;
    unsigned int w0 = eiu[2 * l + 1];
    unsigned int w1 = eiu[2 * (l + 64) + 1];
    const int is64 = __all((w0 | w1) == 0u);
    __syncthreads();

    const int e0 = blockIdx.x * EB1;
    const int e1 = min(e0 + EB1, n_edges);
    for (int e = e0 + threadIdx.x; e < e1; e += 256) {
        int s, d;
        if (is64) {
            const long long* p = (const long long*)ei;
            s = (int)p[e]; d = (int)p[n_edges + e];
        } else {
            const int* p = (const int*)ei;
            s = p[e]; d = p[n_edges + e];
        }
        pk[e]  = ((unsigned int)s << 6) | (unsigned int)(d & (BKT_W - 1));
        int b = d >> 6;
        bkt[e] = (unsigned short)b;
        atomicAdd(&h[b], 1);
    }
    __syncthreads();
    int* out = C + (long long)blockIdx.x * nb1;
    for (int i = threadIdx.x; i < nb1; i += 256) out[i] = h[i];
}

// ---------------------------------------------------------------------------
// Flat exclusive scan of C in bucket-major order (block-local part)
// ---------------------------------------------------------------------------
__global__ __launch_bounds__(1024) void scanA_kernel(
    const int* __restrict__ C, int* __restrict__ Cs,
    int* __restrict__ blockSums, int L, int nb1, int nblk1)
{
    __shared__ int sm[1024];
    const int tid = threadIdx.x;
    const int i = blockIdx.x * 1024 + tid;
    int v = 0;
    if (i < L) {
        int b = i / nblk1, k = i - b * nblk1;
        v = C[(long long)k * nb1 + b];
    }
    int val = v;
    sm[tid] = val;
    __syncthreads();
    for (int off = 1; off < 1024; off <<= 1) {
        int t = (tid >= off) ? sm[tid - off] : 0;
        __syncthreads();
        val += t;
        sm[tid] = val;
        __syncthreads();
    }
    if (i < L) Cs[i] = val - v;
    if (tid == 1023) blockSums[blockIdx.x] = val;
}

// scan3: each block reduces blockSums[0..blockIdx) itself (nbL <= 1024)
__global__ __launch_bounds__(1024) void scan3_kernel(
    int* __restrict__ arr, const int* __restrict__ blockSums, int n)
{
    __shared__ int sm[1024];
    const int tid = threadIdx.x;
    sm[tid] = (tid < blockIdx.x) ? blockSums[tid] : 0;
    __syncthreads();
    #pragma unroll
    for (int off = 512; off > 0; off >>= 1) {
        if (tid < off) sm[tid] += sm[tid + off];
        __syncthreads();
    }
    const int i = blockIdx.x * 1024 + tid;
    if (i < n) arr[i] += sm[0];
}

// ---------------------------------------------------------------------------
// Pass-1 scatter, all windows in one dispatch (win = blockIdx / nblk1)
// ---------------------------------------------------------------------------
__global__ __launch_bounds__(256) void s1_scatter_kernel(
    const unsigned short* __restrict__ bkt, const unsigned int* __restrict__ pk,
    const int* __restrict__ Cs, unsigned int* __restrict__ sorted,
    int n_edges, int nb1, int nblk1)
{
    __shared__ int cur[WIN];
    const int win = blockIdx.x / nblk1;
    const int blk = blockIdx.x - win * nblk1;
    const int lo  = win * WIN;
    const int hi  = min(lo + WIN, nb1);
    for (int t = threadIdx.x; t < hi - lo; t += 256)
        cur[t] = Cs[(long long)(lo + t) * nblk1 + blk];
    __syncthreads();
    const int e0 = blk * EB1;
    const int e1 = min(e0 + EB1, n_edges);
    for (int e = e0 + threadIdx.x; e < e1; e += 256) {
        int b = bkt[e];
        if (b >= lo && b < hi) {
            int pos = atomicAdd(&cur[b - lo], 1);   // LDS atomic
            sorted[pos] = pk[e];
        }
    }
}

// ---------------------------------------------------------------------------
// Merged: blocks [0,nb1) per-bucket LDS counting sort (row_end + sorted in
// place); blocks [nb1,nb1+nbcvt) cvt x f32->bf16; last 256 blocks build Wt.
// Independent work co-resident -> real overlap in one dispatch.
// ---------------------------------------------------------------------------
__global__ __launch_bounds__(256) void sort_prep_kernel(
    unsigned int* __restrict__ sorted, const int* __restrict__ Cs,
    int n_edges, int n_nodes, int nb1, int nblk1, int* __restrict__ row_end,
    const float* __restrict__ x, unsigned short* __restrict__ Xb,
    long long nelem, int nbcvt,
    const float* __restrict__ Wr1, const float* __restrict__ Wl1,
    unsigned short* __restrict__ Wt1,
    const float* __restrict__ Wr2, const float* __restrict__ Wl2,
    unsigned short* __restrict__ Wt2)
{
    __shared__ unsigned int lpk[EMAX];
    __shared__ int h64[BKT_W], excl[BKT_W + 1], cur[BKT_W];
    const int bid = blockIdx.x;
    const int t = threadIdx.x;

    if (bid < nb1) {
        const int b = bid;
        const int base = Cs[(long long)b * nblk1];
        const int nextb = (b + 1 < nb1) ? Cs[(long long)(b + 1) * nblk1] : n_edges;
        const int cnt = min(nextb - base, EMAX);

        if (t < BKT_W) h64[t] = 0;
        for (int i = t; i < cnt; i += 256) lpk[i] = sorted[base + i];
        __syncthreads();
        for (int i = t; i < cnt; i += 256) atomicAdd(&h64[lpk[i] & (BKT_W - 1)], 1);
        __syncthreads();
        if (t == 0) {
            int run = 0;
            #pragma unroll
            for (int i = 0; i < BKT_W; ++i) { excl[i] = run; run += h64[i]; }
            excl[BKT_W] = run;
        }
        __syncthreads();
        const int node0 = b * BKT_W;
        const int bins = min(BKT_W, n_nodes - node0);
        if (t < bins) row_end[node0 + t] = base + excl[t + 1];
        if (t < BKT_W) cur[t] = excl[t];
        __syncthreads();
        for (int i = t; i < cnt; i += 256) {
            unsigned int p = lpk[i];
            int pos = atomicAdd(&cur[p & (BKT_W - 1)], 1);   // LDS atomic
            sorted[base + pos] = p >> 6;                     // src
        }
    } else if (bid < nb1 + nbcvt) {
        const long long i = ((long long)(bid - nb1) * 256 + t) * 8;
        if (i >= nelem) return;
        float4 a = *(const float4*)(x + i);
        float4 c2 = *(const float4*)(x + i + 4);
        bf16x8 v;
        v[0] = (short)f2b(a.x);  v[1] = (short)f2b(a.y);
        v[2] = (short)f2b(a.z);  v[3] = (short)f2b(a.w);
        v[4] = (short)f2b(c2.x); v[5] = (short)f2b(c2.y);
        v[6] = (short)f2b(c2.z); v[7] = (short)f2b(c2.w);
        *(bf16x8*)(Xb + i) = v;
    } else {
        const int cb = bid - nb1 - nbcvt;         // 0..255
        const float* Wr = (cb < 128) ? Wr1 : Wr2;
        const float* Wl = (cb < 128) ? Wl1 : Wl2;
        unsigned short* Wt = (cb < 128) ? Wt1 : Wt2;
        const int c = cb & 127;
        const int k = t;
        float v = (k < 128) ? Wr[k * D + c] : Wl[(k - 128) * D + c];
        Wt[c * KTOT + k] = f2b(v);
    }
}

// ---------------------------------------------------------------------------
// CSR gather aggregation (r7 proven form): wave per node, 16 lanes x uint4,
// 4 edge slots x 4-deep unroll (16 gathers in flight). Plain loads/stores.
// ---------------------------------------------------------------------------
#define ACC8(u) { a0 += blo(u.x); a1 += bhi(u.x); a2 += blo(u.y); a3 += bhi(u.y); \
                  a4 += blo(u.z); a5 += bhi(u.z); a6 += blo(u.w); a7 += bhi(u.w); }

__global__ __launch_bounds__(256) void agg_kernel(
    const unsigned short* __restrict__ src, const int* __restrict__ sorted_src,
    const int* __restrict__ row_end, unsigned short* __restrict__ dst, int n)
{
    const int node = blockIdx.x * 4 + (threadIdx.x >> 6);
    if (node >= n) return;
    const int lane = threadIdx.x & 63;
    const int j = lane >> 4;           // edge slot 0..3
    const int c = (lane & 15) * 8;     // 8 bf16 columns
    const int beg = node ? row_end[node - 1] : 0;
    const int end = row_end[node];

    float a0 = 0.f, a1 = 0.f, a2 = 0.f, a3 = 0.f,
          a4 = 0.f, a5 = 0.f, a6 = 0.f, a7 = 0.f;

    int i = beg + j;
    for (; i + 12 < end; i += 16) {
        int s0 = sorted_src[i];
        int s1 = sorted_src[i + 4];
        int s2 = sorted_src[i + 8];
        int s3 = sorted_src[i + 12];
        uint4 u0 = *(const uint4*)(src + (long long)s0 * D + c);
        uint4 u1 = *(const uint4*)(src + (long long)s1 * D + c);
        uint4 u2 = *(const uint4*)(src + (long long)s2 * D + c);
        uint4 u3 = *(const uint4*)(src + (long long)s3 * D + c);
        ACC8(u0); ACC8(u1); ACC8(u2); ACC8(u3);
    }
    for (; i < end; i += 4) {
        int s0 = sorted_src[i];
        uint4 u0 = *(const uint4*)(src + (long long)s0 * D + c);
        ACC8(u0);
    }

    a0 += __shfl_xor(a0, 16); a1 += __shfl_xor(a1, 16);
    a2 += __shfl_xor(a2, 16); a3 += __shfl_xor(a3, 16);
    a4 += __shfl_xor(a4, 16); a5 += __shfl_xor(a5, 16);
    a6 += __shfl_xor(a6, 16); a7 += __shfl_xor(a7, 16);
    a0 += __shfl_xor(a0, 32); a1 += __shfl_xor(a1, 32);
    a2 += __shfl_xor(a2, 32); a3 += __shfl_xor(a3, 32);
    a4 += __shfl_xor(a4, 32); a5 += __shfl_xor(a5, 32);
    a6 += __shfl_xor(a6, 32); a7 += __shfl_xor(a7, 32);

    if (j == 0) {
        uint4 p;
        p.x = (unsigned int)f2b(a0) | ((unsigned int)f2b(a1) << 16);
        p.y = (unsigned int)f2b(a2) | ((unsigned int)f2b(a3) << 16);
        p.z = (unsigned int)f2b(a4) | ((unsigned int)f2b(a5) << 16);
        p.w = (unsigned int)f2b(a6) | ((unsigned int)f2b(a7) << 16);
        *(uint4*)(dst + (long long)node * D + c) = p;
    }
}

// ---------------------------------------------------------------------------
// MFMA GEMM: out = relu([X|A] @ Wt^T + b). A-fragments direct from global;
// Wt LDS-staged. outp may alias Aop (disjoint per-wave rows).
// ---------------------------------------------------------------------------
template <int OUT_BF16>
__global__ __launch_bounds__(512) void gemm_kernel(
    const unsigned short* __restrict__ Xop, const unsigned short* __restrict__ Aop,
    const unsigned short* __restrict__ Wt, const float* __restrict__ bias,
    void* outp, int n)
{
    __shared__ short sW[D][LSTR];
    const int tid = threadIdx.x;
    const int r0 = blockIdx.x * GM;

    for (int i = 0; i < 8; ++i) {
        int idx = tid + i * 512;
        int r = idx >> 5, c8 = idx & 31;
        bf16x8 w = *(const bf16x8*)(Wt + r * KTOT + c8 * 8);
        *(bf16x8*)&sW[r][c8 * 8] = w;
    }
    __syncthreads();

    const int w    = tid >> 6;
    const int lane = tid & 63;
    const int lr   = lane & 15;
    const int lk   = (lane >> 4) * 8;
    const int row  = r0 + w * 16 + lr;
    const bool rok = (row < n);

    f32x4 acc[8];
    #pragma unroll
    for (int ct = 0; ct < 8; ++ct) acc[ct] = (f32x4){0.f, 0.f, 0.f, 0.f};

    #pragma unroll
    for (int ks = 0; ks < 8; ++ks) {
        bf16x8 a = {};
        if (rok) {
            const unsigned short* base = (ks < 4) ? Xop : Aop;
            a = *(const bf16x8*)(base + (long long)row * D + (ks & 3) * 32 + lk);
        }
        #pragma unroll
        for (int ct = 0; ct < 8; ++ct) {
            bf16x8 bf = *(const bf16x8*)&sW[ct * 16 + lr][ks * 32 + lk];
            acc[ct] = __builtin_amdgcn_mfma_f32_16x16x32_bf16(a, bf, acc[ct], 0, 0, 0);
        }
    }

    // C/D: col = lane&15, row = (lane>>4)*4 + j
    const int rbase = r0 + w * 16 + (lane >> 4) * 4;
    #pragma unroll
    for (int ct = 0; ct < 8; ++ct) {
        const int col = ct * 16 + lr;
        const float bv = bias[col];
        #pragma unroll
        for (int j = 0; j < 4; ++j) {
            int orow = rbase + j;
            if (orow < n) {
                float val = fmaxf(acc[ct][j] + bv, 0.f);
                if (OUT_BF16) {
                    ((unsigned short*)outp)[(long long)orow * D + col] = f2b(val);
                } else {
                    ((float*)outp)[(long long)orow * D + col] = val;
                }
            }
        }
    }
}

static inline size_t align_up(size_t v, size_t a) { return (v + a - 1) & ~(a - 1); }

extern "C" void kernel_launch(void* const* d_in, const int* in_sizes, int n_in,
                              void* d_out, int out_size, void* d_ws, size_t ws_size,
                              hipStream_t stream) {
    const float* x   = (const float*)d_in[0];
    const void*  ei  = d_in[1];
    const float* Wr1 = (const float*)d_in[2];
    const float* Wl1 = (const float*)d_in[3];
    const float* b1  = (const float*)d_in[4];
    const float* Wr2 = (const float*)d_in[5];
    const float* Wl2 = (const float*)d_in[6];
    const float* b2  = (const float*)d_in[7];
    float* out = (float*)d_out;

    const int n_nodes = in_sizes[0] / D;
    const int n_edges = in_sizes[1] / 2;

    const int nb1   = (n_nodes + BKT_W - 1) / BKT_W;
    const int nblk1 = (n_edges + EB1 - 1) / EB1;
    const int L     = nb1 * nblk1;
    const int npass = (nb1 + WIN - 1) / WIN;
    const int nbL   = (L + 1023) / 1024;   // <= 1024 required by scan3

    // ws layout (~58 MB; proven available rounds 2-12)
    char* ws = (char*)d_ws;
    size_t off_rs   = 0;
    size_t off_bs   = align_up(off_rs + 4 * (size_t)(n_nodes + 1), 256);
    size_t off_ssrc = align_up(off_bs + 4 * 1024, 256);
    size_t off_wt1  = align_up(off_ssrc + 4 * (size_t)n_edges, 256);
    size_t off_wt2  = align_up(off_wt1 + 2 * (size_t)D * KTOT, 256);
    size_t off_xb   = align_up(off_wt2 + 2 * (size_t)D * KTOT, 256);
    size_t off_ab   = align_up(off_xb + 2 * (size_t)n_nodes * D, 256);

    int* row_end         = (int*)(ws + off_rs);
    int* blockSums       = (int*)(ws + off_bs);
    unsigned int* sorted = (unsigned int*)(ws + off_ssrc);
    unsigned short* Wt1  = (unsigned short*)(ws + off_wt1);
    unsigned short* Wt2  = (unsigned short*)(ws + off_wt2);
    unsigned short* Xb   = (unsigned short*)(ws + off_xb);
    unsigned short* Ab   = (unsigned short*)(ws + off_ab);
    // pk/bkt alias Xb (dead until sort_prep cvt); C/Cs alias Ab (dead until agg L1)
    unsigned int*   pk  = (unsigned int*)(ws + off_xb);
    unsigned short* bkt = (unsigned short*)(pk + n_edges);
    int* C  = (int*)(ws + off_ab);
    int* Cs = C + L;

    const int gemm_blocks = (n_nodes + GM - 1) / GM;
    const int agg_blocks  = (n_nodes + 3) / 4;
    const long long nfeat = (long long)n_nodes * D;
    const int nbcvt = (int)((nfeat / 8 + 255) / 256);

    // ---- CSR build: two-level counting sort, zero global atomics ----
    pack_count_kernel<<<nblk1, 256, 0, stream>>>(ei, pk, bkt, n_edges, nb1, C);
    scanA_kernel<<<nbL, 1024, 0, stream>>>(C, Cs, blockSums, L, nb1, nblk1);
    scan3_kernel<<<nbL, 1024, 0, stream>>>(Cs, blockSums, L);
    s1_scatter_kernel<<<nblk1 * npass, 256, 0, stream>>>(
        bkt, pk, Cs, sorted, n_edges, nb1, nblk1);

    // ---- merged bucket-sort + prep (pk/bkt dead after scatter) ----
    sort_prep_kernel<<<nb1 + nbcvt + 256, 256, 0, stream>>>(
        sorted, Cs, n_edges, n_nodes, nb1, nblk1, row_end,
        x, Xb, nfeat, nbcvt, Wr1, Wl1, Wt1, Wr2, Wl2, Wt2);

    // ---- layer 1 (agg output overwrites C/Cs — dead now) ----
    agg_kernel<<<agg_blocks, 256, 0, stream>>>(
        Xb, (const int*)sorted, row_end, Ab, n_nodes);
    gemm_kernel<1><<<gemm_blocks, 512, 0, stream>>>(Xb, Ab, Wt1, b1, Ab, n_nodes);

    // ---- layer 2 ----
    agg_kernel<<<agg_blocks, 256, 0, stream>>>(
        Ab, (const int*)sorted, row_end, Xb, n_nodes);
    gemm_kernel<0><<<gemm_blocks, 512, 0, stream>>>(Ab, Xb, Wt2, b2, out, n_nodes);
}